// Round 1
// baseline (809.424 us; speedup 1.0000x reference)
//
#include <hip/hip_runtime.h>
#include <hip/hip_bf16.h>
#include <stdint.h>

#define B_ 4
#define H_ 160
#define W_ 160
#define HW_ 25600

typedef __hip_bfloat16 bf16;
typedef __attribute__((ext_vector_type(8))) short bf16x8;
typedef __attribute__((ext_vector_type(4))) float f32x4;

// ---------------- static workspace (module .bss) ----------------
__device__ float g_A1[6553600];     // (4,64,160,160) conv scratch
__device__ float g_A2[6553600];
__device__ float g_F1[6553600];
__device__ float g_CO[22118400];    // (4,216,160,160); mask channels pre-sigmoided
__device__ __align__(16) bf16 g_X1[6553600];  // NHWC bf16 x for dcn1
__device__ __align__(16) bf16 g_X2[6553600];  // NHWC bf16 x for dcn2
__device__ __align__(16) bf16 g_WB[516096];   // conv weights, B-fragment order
__device__ __align__(16) bf16 g_WD[73728];    // 2 x dcn weights, B-frag, K-permuted

__device__ __forceinline__ const float* rsrc(const float* p, int id) {
  if (id == 1) return g_A1;
  if (id == 2) return g_A2;
  if (id == 3) return g_F1;
  if (id == 4) return g_CO;
  return p;
}
__device__ __forceinline__ float* rdst(float* p, int id) {
  if (id == 1) return g_A1;
  if (id == 2) return g_A2;
  if (id == 3) return g_F1;
  if (id == 4) return g_CO;
  return p;
}
__device__ __forceinline__ const bf16* xsrc(int id) {
  return (id == 5) ? g_X1 : g_X2;
}
__device__ __forceinline__ bf16* xdst(int id) {
  if (id == 5) return g_X1;
  if (id == 6) return g_X2;
  return nullptr;
}

// ---------------- weight prep: conv B-fragment order ----------------
// layout [nb][cc][tap][nt(NTPB)][lane(64)][j(8)]
__global__ void prep_wfrag(const float* __restrict__ src, int off,
                           int OC, int CIN, int NB, int NTPB) {
  int i = blockIdx.x * 256 + threadIdx.x;
  int CC = CIN >> 5;
  int total = NB * CC * 9 * NTPB * 512;
  if (i >= total) return;
  int j = i & 7;
  int t = i >> 3;
  int lane = t & 63; t >>= 6;
  int nt = t % NTPB; t /= NTPB;
  int tap = t % 9; t /= 9;
  int cc = t % CC; int nb = t / CC;
  int oc = nb * (NTPB * 16) + nt * 16 + (lane & 15);
  int ci = cc * 32 + (lane >> 4) * 8 + j;
  float v = (oc < OC) ? src[(oc * CIN + ci) * 9 + tap] : 0.f;
  g_WB[off + i] = __float2bfloat16(v);
}

// dcn weights -> B-frag order with K-permutation k' = g*72 + kk*8 + c
__global__ void prep_wdcnfrag(const float* __restrict__ src, int off) {
  int i = blockIdx.x * 256 + threadIdx.x;
  if (i >= 36864) return;
  int j = i & 7;
  int t = i >> 3;
  int lane = t & 63; t >>= 6;
  int nt = t & 3; int kc = t >> 2;
  int kp = kc * 32 + (lane >> 4) * 8 + j;
  int oc = nt * 16 + (lane & 15);
  int g = kp / 72, r = kp - g * 72;
  int kk = r >> 3, c = r & 7;
  g_WD[off + i] = __float2bfloat16(src[oc * 576 + g * 72 + c * 9 + kk]);
}

// ---------------- NCHW f32 -> NHWC bf16 transpose (64 ch) ----------------
__global__ __launch_bounds__(256)
void nchw2nhwc_bf(const float* __restrict__ in, int out_id) {
  bf16* out = xdst(out_id);
  __shared__ float T[64][65];
  int tid = threadIdx.x;
  int px0 = blockIdx.x * 64;
  int b = blockIdx.y;
#pragma unroll
  for (int it = 0; it < 16; ++it) {
    int idx = it * 256 + tid;
    int c = idx >> 6, px = idx & 63;
    T[c][px] = in[(b * 64 + c) * HW_ + px0 + px];
  }
  __syncthreads();
#pragma unroll
  for (int it = 0; it < 16; ++it) {
    int idx = it * 256 + tid;
    int px = idx >> 6, c = idx & 63;
    out[((size_t)b * HW_ + px0 + px) * 64 + c] = __float2bfloat16(T[c][px]);
  }
}

// B-fragment loader: NT consecutive b128s for one (cc,tap) group.
template<int NT>
__device__ __forceinline__ void ldw(const bf16* wlane, int idx, bf16x8* pb) {
#pragma unroll
  for (int nt = 0; nt < NT; ++nt)
    pb[nt] = *(const bf16x8*)(wlane + (size_t)idx * (NT * 512) + nt * 512);
}

// ---------------- MFMA conv3x3, pad=1, 4x32 px x NT*16 oc per block ----------------
// act: 0 none, 1 lrelu, 2 sigmoid on oc>=144
// Software-pipelined: weight (B-frag) and activation (A-frag) register
// double-buffer, prefetched one tap ahead. CC is a template param so both
// loops fully unroll and all double-buffer indices are compile-time.
template<int NT, int CC>
__global__ __launch_bounds__(256, 3)
void conv_mfma(const float* in1p, int id1, int c1,
               const float* in2p, int id2, int c2,
               int woff, const float* __restrict__ bias,
               float* outp, int out_id, int OC, int act)
{
  const float* in1 = rsrc(in1p, id1);
  const float* in2 = rsrc(in2p, id2);
  float* out = rdst(outp, out_id);

  constexpr int XS_BYTES = 6 * 34 * 40 * 2;        // 16320
  constexpr int OS_BYTES = NT * 16 * 66 * 4;
  constexpr int SH_BYTES = (OS_BYTES > XS_BYTES) ? OS_BYTES : XS_BYTES;
  __shared__ __align__(16) char SH[SH_BYTES];
  bf16* XS = (bf16*)SH;         // [6 rows][34 cols][ci pad 40]
  float* OS = (float*)SH;       // [NT*16 oc][66]

  int tid = threadIdx.x;
  int bx = blockIdx.x;
  int r0 = 4 * (bx / 5), c0 = 32 * (bx % 5);
  int nb = blockIdx.y;
  int b = blockIdx.z;

  int w = tid >> 6;
  int L = tid & 63;
  int lm = L & 15;
  int k0 = (L >> 4) * 8;

  const bf16* wlane = g_WB + woff + (size_t)nb * CC * (9 * NT * 512) + L * 8;

  f32x4 acc[2][NT];
#pragma unroll
  for (int mi = 0; mi < 2; ++mi)
#pragma unroll
    for (int nt = 0; nt < NT; ++nt) acc[mi][nt] = (f32x4)0.f;

  bf16x8 bwb[2][NT];      // weight double-buffer (prefetch 1 tap ahead)
  bf16x8 a0b[2], a1b[2];  // A-frag double-buffer

  // prologue: first tap's weights in flight before first staging
  ldw<NT>(wlane, 0, bwb[0]);

#pragma unroll
  for (int cc = 0; cc < CC; ++cc) {
    int cb = cc * 32;
    __syncthreads();
    {
      int colp = tid & 15, rr = tid >> 4;
      int gx = c0 + 2 * colp;
#pragma unroll
      for (int t = 0; t < 12; ++t) {
        int rc2 = t * 16 + rr;
        int row = rc2 >> 5, ci = rc2 & 31;
        int gy = r0 - 1 + row;
        int gc = cb + ci;
        float2 v = make_float2(0.f, 0.f);
        if (gy >= 0 && gy < H_) {
          const float* src = (gc < c1) ? &in1[((b * c1 + gc) * H_ + gy) * W_ + gx]
                                       : &in2[((b * c2 + gc - c1) * H_ + gy) * W_ + gx];
          v = *(const float2*)src;
        }
        int base = (row * 34 + 1 + 2 * colp) * 40 + ci;
        XS[base] = __float2bfloat16(v.x);
        XS[base + 40] = __float2bfloat16(v.y);
      }
#pragma unroll
      for (int t = 0; t < 2; ++t) {
        int id = t * 256 + tid;
        if (id < 384) {
          int ci = id & 31, rc = id >> 5;
          int row = rc >> 1, col = (rc & 1) * 33;
          int gy = r0 - 1 + row, gxh = c0 - 1 + col;
          int gc = cb + ci;
          float v = 0.f;
          if (gy >= 0 && gy < H_ && gxh >= 0 && gxh < W_)
            v = (gc < c1) ? in1[((b * c1 + gc) * H_ + gy) * W_ + gxh]
                          : in2[((b * c2 + gc - c1) * H_ + gy) * W_ + gxh];
          XS[(row * 34 + col) * 40 + ci] = __float2bfloat16(v);
        }
      }
    }
    __syncthreads();

    // tap-0 A-frags for this cc (parity continues across cc since 9 is odd)
    {
      const int cur0 = (cc * 9) & 1;
      a0b[cur0] = *(const bf16x8*)&XS[(w * 34 + lm) * 40 + k0];
      a1b[cur0] = *(const bf16x8*)&XS[(w * 34 + 16 + lm) * 40 + k0];
    }

#pragma unroll
    for (int tap = 0; tap < 9; ++tap) {
      const int cur = (cc * 9 + tap) & 1;
      const int nxt = cur ^ 1;
      // prefetch next tap (or next cc's tap 0 weights) before this tap's MFMAs
      if (tap < 8) {
        const int t2 = tap + 1;
        const int dy2 = t2 / 3, dx2 = t2 - dy2 * 3;
        ldw<NT>(wlane, cc * 9 + t2, bwb[nxt]);
        a0b[nxt] = *(const bf16x8*)&XS[((w + dy2) * 34 + lm + dx2) * 40 + k0];
        a1b[nxt] = *(const bf16x8*)&XS[((w + dy2) * 34 + 16 + lm + dx2) * 40 + k0];
      } else if (cc + 1 < CC) {
        ldw<NT>(wlane, (cc + 1) * 9, bwb[nxt]);
      }
#pragma unroll
      for (int nt = 0; nt < NT; ++nt) {
        acc[0][nt] = __builtin_amdgcn_mfma_f32_16x16x32_bf16(a0b[cur], bwb[cur][nt], acc[0][nt], 0, 0, 0);
        acc[1][nt] = __builtin_amdgcn_mfma_f32_16x16x32_bf16(a1b[cur], bwb[cur][nt], acc[1][nt], 0, 0, 0);
      }
    }
  }

  for (int pass = 0; pass < 2; ++pass) {
    __syncthreads();
    if ((w >> 1) == pass) {
#pragma unroll
      for (int mi = 0; mi < 2; ++mi)
#pragma unroll
        for (int nt = 0; nt < NT; ++nt)
#pragma unroll
          for (int r = 0; r < 4; ++r) {
            int m_local = 32 * (w & 1) + 16 * mi + (L >> 4) * 4 + r;
            OS[(nt * 16 + lm) * 66 + m_local] = acc[mi][nt][r];
          }
    }
    __syncthreads();
    for (int i = tid; i < NT * 1024; i += 256) {
      int oc_l = i >> 6, m = i & 63;
      int oc = nb * (NT * 16) + oc_l;
      if (oc < OC) {
        float v = OS[oc_l * 66 + m] + bias[oc];
        if (act == 1) v = v > 0.f ? v : 0.1f * v;
        else if (act == 2 && oc >= 144) v = 1.f / (1.f + __expf(-v));
        int px = pass * 64 + m;
        int py = r0 + (px >> 5), pxc = c0 + (px & 31);
        out[((b * OC + oc) * H_ + py) * W_ + pxc] = v;
      }
    }
  }
}

// ---------------- fused modulated deformable conv ----------------
// grid: (800, B). block 256. 32 px x 64 oc. x is NHWC bf16. CO mask pre-sigmoided.
// optionally also writes NHWC bf16 copy of output (xt_out_id 5/6, 0 = none).
#define LO16(u) __uint_as_float((u) << 16)
#define HI16(u) __uint_as_float((u) & 0xffff0000u)

__global__ __launch_bounds__(256)
void dcn_k(int x_id, int wd_off, const float* __restrict__ bias,
           float* outp, int out_id, int xt_out_id)
{
  const bf16* xT = xsrc(x_id);
  const float* co = g_CO;
  const bf16* WD = g_WD + wd_off;               // [18][4][64][8]
  float* out = rdst(outp, out_id);
  __shared__ __align__(16) bf16 vS[32 * 584];
  int tid = threadIdx.x;
  int b = blockIdx.y;
  int h = blockIdx.x / 5;
  int w0 = (blockIdx.x % 5) * 32;
  const bf16* xb = xT + (size_t)b * HW_ * 64;

  // ---- phase A: hoisted co loads, then bf16 gathers ----
  const float* cob = co + ((size_t)b * 216 * HW_) + h * W_ + w0;
  float oy[9], ox[9], mk[9];
#pragma unroll
  for (int t = 0; t < 9; ++t) {
    int idx = t * 256 + tid;
    int gk = idx >> 5, p = idx & 31;
    oy[t] = cob[(gk * 2) * HW_ + p];
    ox[t] = cob[(gk * 2 + 1) * HW_ + p];
    mk[t] = cob[(144 + gk) * HW_ + p];   // pre-sigmoided
  }
#pragma unroll
  for (int t = 0; t < 9; ++t) {
    int idx = t * 256 + tid;
    int gk = idx >> 5, p = idx & 31;
    int g = gk / 9, kk = gk - g * 9;
    float pyf = oy[t] + (float)(kk / 3 - 1 + h);
    float pxf = ox[t] + (float)(kk % 3 - 1 + w0 + p);
    float y0f = floorf(pyf), x0f = floorf(pxf);
    float ly = pyf - y0f, lx = pxf - x0f;
    int iy0 = (int)y0f, ix0 = (int)x0f;
    int iy1 = iy0 + 1, ix1 = ix0 + 1;
    float mask = mk[t];
    float w00 = (1.f - ly) * (1.f - lx) * mask;
    float w01 = (1.f - ly) * lx * mask;
    float w10 = ly * (1.f - lx) * mask;
    float w11 = ly * lx * mask;
    if (iy0 < 0 || iy0 >= H_) { w00 = 0.f; w01 = 0.f; }
    if (iy1 < 0 || iy1 >= H_) { w10 = 0.f; w11 = 0.f; }
    if (ix0 < 0 || ix0 >= W_) { w00 = 0.f; w10 = 0.f; }
    if (ix1 < 0 || ix1 >= W_) { w01 = 0.f; w11 = 0.f; }
    int cy0 = min(max(iy0, 0), H_ - 1), cy1 = min(max(iy1, 0), H_ - 1);
    int cx0 = min(max(ix0, 0), W_ - 1), cx1 = min(max(ix1, 0), W_ - 1);
    int gb = g * 8;
    uint4 u00 = *(const uint4*)(xb + (cy0 * W_ + cx0) * 64 + gb);
    uint4 u01 = *(const uint4*)(xb + (cy0 * W_ + cx1) * 64 + gb);
    uint4 u10 = *(const uint4*)(xb + (cy1 * W_ + cx0) * 64 + gb);
    uint4 u11 = *(const uint4*)(xb + (cy1 * W_ + cx1) * 64 + gb);
    bf16 tmp[8];
#define LERP2(ci, A, Bq, Cq, Dq) { \
    float vlo = w00 * LO16(A) + w01 * LO16(Bq) + w10 * LO16(Cq) + w11 * LO16(Dq); \
    float vhi = w00 * HI16(A) + w01 * HI16(Bq) + w10 * HI16(Cq) + w11 * HI16(Dq); \
    tmp[2*(ci)] = __float2bfloat16(vlo); tmp[2*(ci)+1] = __float2bfloat16(vhi); }
    LERP2(0, u00.x, u01.x, u10.x, u11.x);
    LERP2(1, u00.y, u01.y, u10.y, u11.y);
    LERP2(2, u00.z, u01.z, u10.z, u11.z);
    LERP2(3, u00.w, u01.w, u10.w, u11.w);
#undef LERP2
    *(uint4*)&vS[p * 584 + g * 72 + kk * 8] = *(const uint4*)tmp;
  }
  __syncthreads();

  // ---- phase B: MFMA ----
  int w = tid >> 6;
  int L = tid & 63;
  int lm = L & 15;
  int k0 = (L >> 4) * 8;
  int mt = w & 1;
  int nb2 = (w >> 1) * 2;
  f32x4 acc2[2];
  acc2[0] = (f32x4)0.f; acc2[1] = (f32x4)0.f;
#pragma unroll 3
  for (int kc = 0; kc < 18; ++kc) {
    bf16x8 a = *(const bf16x8*)&vS[(mt * 16 + lm) * 584 + kc * 32 + k0];
#pragma unroll
    for (int i = 0; i < 2; ++i) {
      bf16x8 bw = *(const bf16x8*)(WD + ((kc * 4 + nb2 + i) * 64 + L) * 8);
      acc2[i] = __builtin_amdgcn_mfma_f32_16x16x32_bf16(a, bw, acc2[i], 0, 0, 0);
    }
  }
  __syncthreads();

  // ---- epilogue through LDS ----
  float* outS = (float*)vS;          // [64 oc][33]
#pragma unroll
  for (int i = 0; i < 2; ++i)
#pragma unroll
    for (int r = 0; r < 4; ++r) {
      int oc = (nb2 + i) * 16 + lm;
      int px = mt * 16 + (L >> 4) * 4 + r;
      outS[oc * 33 + px] = acc2[i][r];
    }
  __syncthreads();
  for (int i = tid; i < 2048; i += 256) {
    int oc = i >> 5, p2 = i & 31;
    float v = outS[oc * 33 + p2] + bias[oc];
    v = v > 0.f ? v : 0.1f * v;
    int oi = ((b * 64 + oc) * H_ + h) * W_ + w0 + p2;
    out[oi] = v;
  }
  if (xt_out_id) {
    bf16* xt = xdst(xt_out_id);
    for (int i = tid; i < 2048; i += 256) {
      int p2 = i >> 6, c = i & 63;
      float v = outS[c * 33 + p2] + bias[c];
      v = v > 0.f ? v : 0.1f * v;
      xt[((size_t)b * HW_ + h * W_ + w0 + p2) * 64 + c] = __float2bfloat16(v);
    }
  }
}

extern "C" void kernel_launch(void* const* d_in, const int* in_sizes, int n_in,
                              void* d_out, int out_size, void* d_ws, size_t ws_size,
                              hipStream_t stream) {
  (void)in_sizes; (void)n_in; (void)out_size; (void)d_ws; (void)ws_size;
  const float* nbr    = (const float*)d_in[0];
  const float* ref    = (const float*)d_in[1];
  const float* w_off1 = (const float*)d_in[2];
  const float* b_off1 = (const float*)d_in[3];
  const float* w_off2 = (const float*)d_in[4];
  const float* b_off2 = (const float*)d_in[5];
  const float* w_co   = (const float*)d_in[6];
  const float* b_co   = (const float*)d_in[7];
  const float* w_dcn  = (const float*)d_in[8];
  const float* b_dcn  = (const float*)d_in[9];
  const float* w_coff1= (const float*)d_in[10];
  const float* b_coff1= (const float*)d_in[11];
  const float* w_coff2= (const float*)d_in[12];
  const float* b_coff2= (const float*)d_in[13];
  const float* w_cco  = (const float*)d_in[14];
  const float* b_cco  = (const float*)d_in[15];
  const float* w_cdcn = (const float*)d_in[16];
  const float* b_cdcn = (const float*)d_in[17];

  prep_wfrag<<<288, 256, 0, stream>>>(w_off1, 0, 64, 128, 1, 4);
  prep_wfrag<<<144, 256, 0, stream>>>(w_off2, 73728, 64, 64, 1, 4);
  prep_wfrag<<<504, 256, 0, stream>>>(w_co, 110592, 216, 64, 2, 7);
  prep_wfrag<<<288, 256, 0, stream>>>(w_coff1, 239616, 64, 128, 1, 4);
  prep_wfrag<<<144, 256, 0, stream>>>(w_coff2, 313344, 64, 64, 1, 4);
  prep_wfrag<<<504, 256, 0, stream>>>(w_cco, 350208, 216, 64, 2, 7);
  prep_wdcnfrag<<<144, 256, 0, stream>>>(w_dcn, 0);
  prep_wdcnfrag<<<144, 256, 0, stream>>>(w_cdcn, 36864);

  dim3 blk(256);
  float* out = (float*)d_out;
  // X1 = NHWC bf16(nbr)
  nchw2nhwc_bf<<<dim3(400, 4), blk, 0, stream>>>(nbr, 5);
  // A1 = lrelu(conv(cat(nbr,ref))); A2 = lrelu(conv(A1)); CO = conv(A2)
  conv_mfma<4,4><<<dim3(200, 1, 4), blk, 0, stream>>>(nbr, 0, 64, ref, 0, 64, 0, b_off1, nullptr, 1, 64, 1);
  conv_mfma<4,2><<<dim3(200, 1, 4), blk, 0, stream>>>(nullptr, 1, 64, nullptr, 0, 0, 73728, b_off2, nullptr, 2, 64, 1);
  conv_mfma<7,2><<<dim3(200, 2, 4), blk, 0, stream>>>(nullptr, 2, 64, nullptr, 0, 0, 110592, b_co, nullptr, 4, 216, 2);
  // F1 = lrelu(dcn(X1, CO)) -> also X2 (NHWC bf16)
  dcn_k<<<dim3(800, 4), blk, 0, stream>>>(5, 0, b_dcn, nullptr, 3, 6);
  // cascade
  conv_mfma<4,4><<<dim3(200, 1, 4), blk, 0, stream>>>(nullptr, 3, 64, ref, 0, 64, 239616, b_coff1, nullptr, 1, 64, 1);
  conv_mfma<4,2><<<dim3(200, 1, 4), blk, 0, stream>>>(nullptr, 1, 64, nullptr, 0, 0, 313344, b_coff2, nullptr, 2, 64, 1);
  conv_mfma<7,2><<<dim3(200, 2, 4), blk, 0, stream>>>(nullptr, 2, 64, nullptr, 0, 0, 350208, b_cco, nullptr, 4, 216, 2);
  // out = lrelu(dcn(X2, CO))
  dcn_k<<<dim3(800, 4), blk, 0, stream>>>(6, 36864, b_cdcn, out, 0, 0);
}